// Round 1
// baseline (388.065 us; speedup 1.0000x reference)
//
#include <hip/hip_runtime.h>
#include <hip/hip_bf16.h>
#include <stdint.h>

typedef __attribute__((ext_vector_type(8))) short short8;           // 8 bf16 (4 VGPR) MFMA frag
typedef __attribute__((ext_vector_type(4))) float f32x4;            // MFMA acc
typedef __attribute__((ext_vector_type(4))) unsigned short ushort4_t;
typedef __attribute__((ext_vector_type(8))) unsigned short ushort8_t;

#define K_TOT 4096
#define N_TOT 4096

static __device__ __forceinline__ unsigned short f2bf(float f) {
    union { float f; unsigned int u; } v; v.f = f;
    unsigned int u = v.u;
    u += 0x7fffu + ((u >> 16) & 1u);   // round-to-nearest-even
    return (unsigned short)(u >> 16);
}

// ---------------- prepass: x fp32 -> bf16 (vectorized 32B read / 16B write) -------------
__global__ void cvt_x_kernel(const float4* __restrict__ x, ushort8_t* __restrict__ out, long n8) {
    long i = (long)blockIdx.x * blockDim.x + threadIdx.x;
    long stride = (long)gridDim.x * blockDim.x;
    for (; i < n8; i += stride) {
        float4 a = x[2 * i], b = x[2 * i + 1];
        ushort8_t r;
        r[0] = f2bf(a.x); r[1] = f2bf(a.y); r[2] = f2bf(a.z); r[3] = f2bf(a.w);
        r[4] = f2bf(b.x); r[5] = f2bf(b.y); r[6] = f2bf(b.z); r[7] = f2bf(b.w);
        out[i] = r;
    }
}

// ---------------- prepass: w = (wq - zp) -> bf16 (exact: |v| <= 255 fits 8 sig bits) ----
__global__ void cvt_w_kernel(const int4* __restrict__ wq, const int* __restrict__ zp,
                             ushort4_t* __restrict__ out) {
    int o = blockIdx.x;
    int z = zp[o];
    const int4* src = wq + (long)o * (K_TOT / 4);
    ushort4_t* dst = out + (long)o * (K_TOT / 4);
    for (int t = threadIdx.x; t < K_TOT / 4; t += blockDim.x) {
        int4 q = src[t];
        ushort4_t r;
        r[0] = f2bf((float)(q.x - z)); r[1] = f2bf((float)(q.y - z));
        r[2] = f2bf((float)(q.z - z)); r[3] = f2bf((float)(q.w - z));
        dst[t] = r;
    }
}

// ---------------- main GEMM: C[M,N] = A[M,K] * B[N,K]^T, fused scale/bias epilogue ------
// m97 structure: 128x128 tile, 4 waves (2x2), BK=32, global_load_lds width=16,
// mfma_f32_16x16x32_bf16, 4x4 fragments per wave.
__launch_bounds__(256)
__global__ void gemm_bt_kernel(const unsigned short* __restrict__ A,   // [M][K] bf16
                               const unsigned short* __restrict__ B,   // [N][K] bf16
                               const float* __restrict__ scale,
                               const float* __restrict__ bias,
                               float* __restrict__ C, int nbm) {
    __shared__ unsigned short As[128 * 32];   // 8 KB
    __shared__ unsigned short Bs[128 * 32];   // 8 KB

    const int nbx = N_TOT / 128;              // 32
    const int bid = blockIdx.x;
    const int bm = bid / nbx, bn = bid % nbx;

    const int tid = threadIdx.x;
    const int wave = tid >> 6, lane = tid & 63;
    const int wr = wave >> 1, wc = wave & 1;  // 2x2 wave grid, 64x64 per wave

    f32x4 acc[4][4] = {};

    const long a_base = (long)bm * 128 * K_TOT;
    const long b_base = (long)bn * 128 * K_TOT;

    // per-lane staging geometry: chunk c = wave*2 + r covers LDS bytes [c*1024, c*1024+1024)
    // element e = c*64 + lane; tile row = e>>2; 16B column chunk = e&3
    const int krow = lane >> 4;   // 0..3 (k-slice of fragment)
    const int fr = lane & 15;     // fragment row/col

    for (int k0 = 0; k0 < K_TOT; k0 += 32) {
#pragma unroll
        for (int r = 0; r < 2; ++r) {
            int c = wave * 2 + r;
            int e = c * 64 + lane;
            int row = e >> 2, col16 = e & 3;
            const unsigned short* gA = A + a_base + (long)row * K_TOT + k0 + col16 * 8;
            const unsigned short* gB = B + b_base + (long)row * K_TOT + k0 + col16 * 8;
            __builtin_amdgcn_global_load_lds(
                (const __attribute__((address_space(1))) void*)gA,
                (__attribute__((address_space(3))) void*)&As[c * 512], 16, 0, 0);
            __builtin_amdgcn_global_load_lds(
                (const __attribute__((address_space(1))) void*)gB,
                (__attribute__((address_space(3))) void*)&Bs[c * 512], 16, 0, 0);
        }
        __syncthreads();

        short8 a[4], b[4];
#pragma unroll
        for (int m = 0; m < 4; ++m)
            a[m] = *(const short8*)&As[(wr * 64 + m * 16 + fr) * 32 + krow * 8];
#pragma unroll
        for (int n = 0; n < 4; ++n)
            b[n] = *(const short8*)&Bs[(wc * 64 + n * 16 + fr) * 32 + krow * 8];

#pragma unroll
        for (int m = 0; m < 4; ++m)
#pragma unroll
            for (int n = 0; n < 4; ++n)
                acc[m][n] = __builtin_amdgcn_mfma_f32_16x16x32_bf16(a[m], b[n], acc[m][n], 0, 0, 0);
        __syncthreads();
    }

    // epilogue: y = scale[col]*acc + bias[col]
    const int fq = lane >> 4;
#pragma unroll
    for (int n = 0; n < 4; ++n) {
        int col = bn * 128 + wc * 64 + n * 16 + fr;
        float s = scale[col], bb = bias[col];
#pragma unroll
        for (int m = 0; m < 4; ++m) {
            int row0 = bm * 128 + wr * 64 + m * 16 + fq * 4;
#pragma unroll
            for (int j = 0; j < 4; ++j)
                C[(long)(row0 + j) * N_TOT + col] = acc[m][n][j] * s + bb;
        }
    }
}

// ---------------- fallback (only if d_ws too small): fp32 tiled GEMM, correct but slow --
__global__ void fallback_kernel(const float* __restrict__ x, const int* __restrict__ wq,
                                const int* __restrict__ zp, const float* __restrict__ sc,
                                const float* __restrict__ bs, float* __restrict__ y) {
    __shared__ float xs[32][33];
    __shared__ float ws[32][33];
    int bm = blockIdx.y, bn = blockIdx.x;
    int tid = threadIdx.x;
    int r = tid >> 5, c = tid & 31;
    float acc[4] = {0.f, 0.f, 0.f, 0.f};
    for (int k0 = 0; k0 < K_TOT; k0 += 32) {
        for (int t = tid; t < 32 * 32; t += 256) {
            int rr = t >> 5, cc = t & 31;
            xs[rr][cc] = x[(long)(bm * 32 + rr) * K_TOT + k0 + cc];
            int o = bn * 32 + rr;
            ws[rr][cc] = (float)(wq[(long)o * K_TOT + k0 + cc] - zp[o]);
        }
        __syncthreads();
#pragma unroll
        for (int kk = 0; kk < 32; ++kk) {
            float wv = ws[c][kk];
#pragma unroll
            for (int j = 0; j < 4; ++j) acc[j] += xs[r + 8 * j][kk] * wv;
        }
        __syncthreads();
    }
    int o = bn * 32 + c;
    float s = sc[o], b = bs[o];
#pragma unroll
    for (int j = 0; j < 4; ++j)
        y[(long)(bm * 32 + r + 8 * j) * N_TOT + o] = acc[j] * s + b;
}

extern "C" void kernel_launch(void* const* d_in, const int* in_sizes, int n_in,
                              void* d_out, int out_size, void* d_ws, size_t ws_size,
                              hipStream_t stream) {
    const float* x = (const float*)d_in[0];
    const int* wq = (const int*)d_in[1];
    const int* zp = (const int*)d_in[2];
    const float* sc = (const float*)d_in[3];
    const float* bs = (const float*)d_in[4];
    float* y = (float*)d_out;

    const long M = (long)in_sizes[0] / K_TOT;   // 8192

    size_t xb_bytes = (size_t)M * K_TOT * 2;          // 67 MB
    size_t wb_bytes = (size_t)N_TOT * K_TOT * 2;      // 33.5 MB

    if (ws_size >= xb_bytes + wb_bytes && (M & 127) == 0) {
        unsigned short* xb = (unsigned short*)d_ws;
        unsigned short* wb = (unsigned short*)((char*)d_ws + xb_bytes);
        long n8 = M * K_TOT / 8;
        cvt_x_kernel<<<2048, 256, 0, stream>>>((const float4*)x, (ushort8_t*)xb, n8);
        cvt_w_kernel<<<N_TOT, 256, 0, stream>>>((const int4*)wq, zp, (ushort4_t*)wb);
        dim3 grid((unsigned)((M / 128) * (N_TOT / 128)));
        gemm_bt_kernel<<<grid, 256, 0, stream>>>(xb, wb, sc, bs, y, (int)(M / 128));
    } else {
        dim3 grid(N_TOT / 32, (unsigned)(M / 32));
        fallback_kernel<<<grid, 256, 0, stream>>>(x, wq, zp, sc, bs, y);
    }
}

// Round 2
// 302.401 us; speedup vs baseline: 1.2833x; 1.2833x over previous
//
#include <hip/hip_runtime.h>
#include <hip/hip_bf16.h>
#include <stdint.h>

typedef __attribute__((ext_vector_type(8))) short short8;           // 8 bf16 (4 VGPR) MFMA frag
typedef __attribute__((ext_vector_type(4))) float f32x4;            // MFMA acc
typedef __attribute__((ext_vector_type(4))) unsigned short ushort4_t;
typedef __attribute__((ext_vector_type(8))) unsigned short ushort8_t;

#define K_TOT 4096
#define N_TOT 4096

static __device__ __forceinline__ unsigned short f2bf(float f) {
    union { float f; unsigned int u; } v; v.f = f;
    unsigned int u = v.u;
    u += 0x7fffu + ((u >> 16) & 1u);   // round-to-nearest-even
    return (unsigned short)(u >> 16);
}

// ---------------- prepass: x fp32 -> bf16 -------------------------------------------
__global__ void cvt_x_kernel(const float4* __restrict__ x, ushort8_t* __restrict__ out, long n8) {
    long i = (long)blockIdx.x * blockDim.x + threadIdx.x;
    long stride = (long)gridDim.x * blockDim.x;
    for (; i < n8; i += stride) {
        float4 a = x[2 * i], b = x[2 * i + 1];
        ushort8_t r;
        r[0] = f2bf(a.x); r[1] = f2bf(a.y); r[2] = f2bf(a.z); r[3] = f2bf(a.w);
        r[4] = f2bf(b.x); r[5] = f2bf(b.y); r[6] = f2bf(b.z); r[7] = f2bf(b.w);
        out[i] = r;
    }
}

// ---------------- prepass: w = (wq - zp) -> bf16 (exact, |v|<=255) ------------------
__global__ void cvt_w_kernel(const int4* __restrict__ wq, const int* __restrict__ zp,
                             ushort4_t* __restrict__ out) {
    int o = blockIdx.x;
    int z = zp[o];
    const int4* src = wq + (long)o * (K_TOT / 4);
    ushort4_t* dst = out + (long)o * (K_TOT / 4);
    for (int t = threadIdx.x; t < K_TOT / 4; t += blockDim.x) {
        int4 q = src[t];
        ushort4_t r;
        r[0] = f2bf((float)(q.x - z)); r[1] = f2bf((float)(q.y - z));
        r[2] = f2bf((float)(q.z - z)); r[3] = f2bf((float)(q.w - z));
        dst[t] = r;
    }
}

// ================= 256x256 8-phase GEMM (m201 template, plain HIP) ==================
// C[M,N] = A[M,K] * B[N,K]^T, epilogue y = scale[n]*acc + bias[n].
// 8 waves (2M x 4N), per-wave 128x64 out; BK=64, 2 K-tiles/iter, 128 KiB LDS dbuf.
// Swizzle: LDS dest linear (global_load_lds), 16B-chunk XOR (row&7) applied on the
// GLOBAL source and identically on the ds_read -> conflict-free b128 reads.

template<int MH>
__device__ __forceinline__ void read_a(short8 (&a)[4][2], const unsigned short* Ab,
                                       int fr, int krow) {
    const int sw = fr & 7;
#pragma unroll
    for (int mi = 0; mi < 4; ++mi) {
        const int row = (MH * 4 + mi) * 16 + fr;
#pragma unroll
        for (int kk = 0; kk < 2; ++kk)
            a[mi][kk] = *(const short8*)&Ab[row * 64 + (((kk << 2) | krow) ^ sw) * 8];
    }
}

template<int NH>
__device__ __forceinline__ void read_b(short8 (&b)[2][2], const unsigned short* Bb,
                                       int rb, int fr, int krow) {
    const int sw = fr & 7;
#pragma unroll
    for (int ni = 0; ni < 2; ++ni) {
        const int row = rb + (NH * 2 + ni) * 16 + fr;
#pragma unroll
        for (int kk = 0; kk < 2; ++kk)
            b[ni][kk] = *(const short8*)&Bb[row * 64 + (((kk << 2) | krow) ^ sw) * 8];
    }
}

template<int MH, int NH>
__device__ __forceinline__ void mfma16(f32x4 (&acc)[8][4], short8 (&a)[4][2], short8 (&b)[2][2]) {
    __builtin_amdgcn_s_setprio(1);
#pragma unroll
    for (int kk = 0; kk < 2; ++kk)
#pragma unroll
        for (int mi = 0; mi < 4; ++mi)
#pragma unroll
            for (int ni = 0; ni < 2; ++ni)
                acc[MH * 4 + mi][NH * 2 + ni] = __builtin_amdgcn_mfma_f32_16x16x32_bf16(
                    a[mi][kk], b[ni][kk], acc[MH * 4 + mi][NH * 2 + ni], 0, 0, 0);
    __builtin_amdgcn_s_setprio(0);
}

#define BAR() __builtin_amdgcn_s_barrier()
#define LGKM0() asm volatile("s_waitcnt lgkmcnt(0)" ::: "memory")
#define VMCNT2() asm volatile("s_waitcnt vmcnt(2)" ::: "memory")
#define VMCNT0() asm volatile("s_waitcnt vmcnt(0)" ::: "memory")

__launch_bounds__(512, 2)
__global__ void gemm256_kernel(const unsigned short* __restrict__ A,   // [M][K] bf16
                               const unsigned short* __restrict__ B,   // [N][K] bf16
                               const float* __restrict__ scale,
                               const float* __restrict__ bias,
                               float* __restrict__ C, int nbm) {
    __shared__ unsigned short lds[4][2][128 * 64];   // [buf*2+mat][half][row*64+col] 128 KiB

    const int nbn = N_TOT / 256;                     // 16
    int bid = blockIdx.x;
    const int nwg = gridDim.x;
    if ((nwg & 7) == 0) {                            // T1: bijective XCD swizzle
        const int cpx = nwg >> 3;
        bid = (bid & 7) * cpx + (bid >> 3);
    }
    const int bm = bid / nbn, bn = bid % nbn;

    const int tid = threadIdx.x;
    const int w = tid >> 6, lane = tid & 63;
    const int wr = w >> 2, wc = w & 3;               // 2x4 wave grid
    const int fr = lane & 15, krow = lane >> 4;
    const int brb = (wc & 1) * 64;                   // B row base within half

    const long a_row0 = (long)bm * 256;
    const long b_row0 = (long)bn * 256;

    f32x4 acc[8][4] = {};
    short8 afr[4][2], bfr[2][2];

    // stage one half-tile (128 rows x 64 cols bf16): 2 x global_load_lds / thread,
    // linear LDS dest, inverse-swizzled global source chunk.
    auto stage = [&](int t, int mat, int half) {
        const unsigned short* G = (mat == 0) ? A : B;
        const long row0 = ((mat == 0) ? a_row0 : b_row0) + half * 128;
        unsigned short* lb = &lds[(t & 1) * 2 + mat][half][0];
#pragma unroll
        for (int r = 0; r < 2; ++r) {
            const int ck = w * 2 + r;                       // 1 KiB chunk id 0..15
            const int row = ck * 8 + (lane >> 3);           // 0..127
            const int c = (lane & 7) ^ (row & 7);           // pre-swizzled 16B chunk
            const unsigned short* g = G + (row0 + row) * K_TOT + (long)t * 64 + c * 8;
            __builtin_amdgcn_global_load_lds(
                (const __attribute__((address_space(1))) void*)g,
                (__attribute__((address_space(3))) void*)(lb + ck * 512), 16, 0, 0);
        }
    };

    const unsigned short* Ab0 = &lds[0][wr][0];
    const unsigned short* Bb0 = &lds[1][wc >> 1][0];
    const unsigned short* Ab1 = &lds[2][wr][0];
    const unsigned short* Bb1 = &lds[3][wc >> 1][0];

    // prologue: T0 fully + T1.A.h0; allow T1.A.h0 outstanding
    stage(0, 0, 0); stage(0, 0, 1); stage(0, 1, 0); stage(0, 1, 1);
    stage(1, 0, 0);
    VMCNT2();
    BAR();

    const int NIT = K_TOT / 128;                     // 32
#pragma unroll 1
    for (int it = 0; it < NIT; ++it) {
        const int t1 = 2 * it + 1, t2 = 2 * it + 2, t3 = 2 * it + 3;
        const bool nl = (it != NIT - 1);

        // ---------- buf0 : tile t0 ----------
        // p1 q(0,0)
        read_a<0>(afr, Ab0, fr, krow);
        read_b<0>(bfr, Bb0, brb, fr, krow);
        stage(t1, 0, 1);
        BAR(); LGKM0();
        mfma16<0, 0>(acc, afr, bfr);
        BAR();
        // p2 q(0,1)
        read_b<1>(bfr, Bb0, brb, fr, krow);
        stage(t1, 1, 0);
        BAR(); LGKM0();
        mfma16<0, 1>(acc, afr, bfr);
        BAR();
        // p3 q(1,1)
        read_a<1>(afr, Ab0, fr, krow);
        stage(t1, 1, 1);
        BAR(); LGKM0();
        mfma16<1, 1>(acc, afr, bfr);
        BAR();
        // p4 q(1,0)  [K-tile boundary: counted vmcnt guards T1 before p5 reads]
        read_b<0>(bfr, Bb0, brb, fr, krow);
        if (nl) stage(t2, 0, 0);
        BAR(); LGKM0();
        mfma16<1, 0>(acc, afr, bfr);
        if (nl) { VMCNT2(); } else { VMCNT0(); }
        BAR();

        // ---------- buf1 : tile t1 ----------
        // p5 q(0,0)
        read_a<0>(afr, Ab1, fr, krow);
        read_b<0>(bfr, Bb1, brb, fr, krow);
        if (nl) stage(t2, 0, 1);
        BAR(); LGKM0();
        mfma16<0, 0>(acc, afr, bfr);
        BAR();
        // p6 q(0,1)
        read_b<1>(bfr, Bb1, brb, fr, krow);
        if (nl) stage(t2, 1, 0);
        BAR(); LGKM0();
        mfma16<0, 1>(acc, afr, bfr);
        BAR();
        // p7 q(1,1)
        read_a<1>(afr, Ab1, fr, krow);
        if (nl) stage(t2, 1, 1);
        BAR(); LGKM0();
        mfma16<1, 1>(acc, afr, bfr);
        BAR();
        // p8 q(1,0)  [K-tile boundary: counted vmcnt guards T2 before next p1 reads]
        read_b<0>(bfr, Bb1, brb, fr, krow);
        if (nl) stage(t3, 0, 0);
        BAR(); LGKM0();
        mfma16<1, 0>(acc, afr, bfr);
        if (nl) { VMCNT2(); } else { VMCNT0(); }
        BAR();
    }

    // epilogue: y = scale[col]*acc + bias[col]
#pragma unroll
    for (int n = 0; n < 4; ++n) {
        const int col = (int)b_row0 + wc * 64 + n * 16 + fr;
        const float s = scale[col], bb = bias[col];
#pragma unroll
        for (int m = 0; m < 8; ++m) {
            const long row0 = a_row0 + wr * 128 + m * 16 + krow * 4;
#pragma unroll
            for (int j = 0; j < 4; ++j)
                C[(row0 + j) * N_TOT + col] = acc[m][n][j] * s + bb;
        }
    }
}

// ---------------- fallback (ws too small / M%256!=0): fp32 tiled GEMM ----------------
__global__ void fallback_kernel(const float* __restrict__ x, const int* __restrict__ wq,
                                const int* __restrict__ zp, const float* __restrict__ sc,
                                const float* __restrict__ bs, float* __restrict__ y) {
    __shared__ float xs[32][33];
    __shared__ float ws[32][33];
    int bm = blockIdx.y, bn = blockIdx.x;
    int tid = threadIdx.x;
    int r = tid >> 5, c = tid & 31;
    float acc[4] = {0.f, 0.f, 0.f, 0.f};
    for (int k0 = 0; k0 < K_TOT; k0 += 32) {
        for (int t = tid; t < 32 * 32; t += 256) {
            int rr = t >> 5, cc = t & 31;
            xs[rr][cc] = x[(long)(bm * 32 + rr) * K_TOT + k0 + cc];
            int o = bn * 32 + rr;
            ws[rr][cc] = (float)(wq[(long)o * K_TOT + k0 + cc] - zp[o]);
        }
        __syncthreads();
#pragma unroll
        for (int kk = 0; kk < 32; ++kk) {
            float wv = ws[c][kk];
#pragma unroll
            for (int j = 0; j < 4; ++j) acc[j] += xs[r + 8 * j][kk] * wv;
        }
        __syncthreads();
    }
    int o = bn * 32 + c;
    float s = sc[o], b = bs[o];
#pragma unroll
    for (int j = 0; j < 4; ++j)
        y[(long)(bm * 32 + r + 8 * j) * N_TOT + o] = acc[j] * s + b;
}

extern "C" void kernel_launch(void* const* d_in, const int* in_sizes, int n_in,
                              void* d_out, int out_size, void* d_ws, size_t ws_size,
                              hipStream_t stream) {
    const float* x = (const float*)d_in[0];
    const int* wq = (const int*)d_in[1];
    const int* zp = (const int*)d_in[2];
    const float* sc = (const float*)d_in[3];
    const float* bs = (const float*)d_in[4];
    float* y = (float*)d_out;

    const long M = (long)in_sizes[0] / K_TOT;   // 8192

    size_t xb_bytes = (size_t)M * K_TOT * 2;          // 67 MB
    size_t wb_bytes = (size_t)N_TOT * K_TOT * 2;      // 33.5 MB

    if (ws_size >= xb_bytes + wb_bytes && (M & 255) == 0) {
        unsigned short* xb = (unsigned short*)d_ws;
        unsigned short* wb = (unsigned short*)((char*)d_ws + xb_bytes);
        long n8 = M * K_TOT / 8;
        cvt_x_kernel<<<2048, 256, 0, stream>>>((const float4*)x, (ushort8_t*)xb, n8);
        cvt_w_kernel<<<N_TOT, 256, 0, stream>>>((const int4*)wq, zp, (ushort4_t*)wb);
        dim3 grid((unsigned)((M / 256) * (N_TOT / 256)));   // 512
        gemm256_kernel<<<grid, 512, 0, stream>>>(xb, wb, sc, bs, y, (int)(M / 256));
    } else {
        dim3 grid(N_TOT / 32, (unsigned)(M / 32));
        fallback_kernel<<<grid, 256, 0, stream>>>(x, wq, zp, sc, bs, y);
    }
}